// Round 8
// baseline (218.507 us; speedup 1.0000x reference)
//
#include <hip/hip_runtime.h>
#include <hip/hip_bf16.h>

// SupCon loss, N=8192, D=128, T=0.1.
// R7: TWO regular nodes (no cooperative launch, no grid sync).
//   A: prep_kernel — blocks <2048 normalize rows -> xsw (swizzled bf16), zero
//      se_acc/done; blocks 2048..3047 = per-class csum FROM RAW EMB (local
//      re-normalize of ~8 member rows, LDS-buffered), writing cd/sd/cm1.
//   B: main_kernel — R5 triangular Gram tile-jobs (LDS-staged B) + last-block
//      finalize via device-scope done-counter (threadfence + atomicAdd).
//
// Math: loss_i = (cm1_i*lse_i - 10*(cd_i - sd_i))/(cm1_i+tiny)
//   lse_i = 10 + ln(sum_{j!=i} e^{s_ij-10})  (constant shift exact; s<=10)
//   cd_i = x_i . classsum[lab_i], sd_i = x_i . x_i (bf16-rounded, matches MFMA)
//   se accumulated INCLUDING diagonal; diag e^{10*sd-10} subtracted at finalize.
//   Symmetry: tile (I,ct): ct>I feeds rows AND cols; ct==I rows only.

typedef __bf16 bf16_t;
typedef __bf16 bf16x2 __attribute__((ext_vector_type(2)));
typedef __bf16 bf16x8 __attribute__((ext_vector_type(8)));
typedef float f32x16 __attribute__((ext_vector_type(16)));

#define NN 8192
#define DIM 128
#define NJOBS 2080                // sum_{cq=0}^{63}(cq+1)
#define SMALL_VAL 1.17549435e-38f
#define L2E10 14.4269504089f      // 10*log2(e)
#define LN2 0.69314718056f

// Swizzle: X[row][d] at (row>>5)*4096 + (d>>4)*512 + ((d>>3)&1)*256 + (row&31)*8 + (d&7)
// Lane l holds dims (2l,2l+1): f=l>>3, hh=(l>>2)&1, j=(l&3)*2 (pair contiguous).
__device__ inline size_t swz(int row, int lane) {
    int f = lane >> 3, hh = (lane >> 2) & 1, j = (lane & 3) << 1;
    return ((size_t)(row >> 5) * 4096) + f * 512 + hh * 256 + (row & 31) * 8 + j;
}

// --- A: normalize (blocks <2048) | per-class csum from raw emb (blocks >=2048) ---
__global__ __launch_bounds__(256) void prep_kernel(const float* __restrict__ emb,
                                                   const int* __restrict__ labels,
                                                   bf16_t* __restrict__ xsw,
                                                   float* __restrict__ cd_arr,
                                                   float* __restrict__ sd_arr,
                                                   float* __restrict__ cm1_arr,
                                                   float* __restrict__ se_acc,
                                                   int* __restrict__ done) {
    __shared__ bf16x2 xloc[96][64];      // member rows, bf16 (csum role)
    __shared__ float cs[DIM];
    __shared__ int rowlist[96];
    __shared__ int nrows;
    int wv = threadIdx.x >> 6, lane = threadIdx.x & 63;

    if (blockIdx.x < 2048) {             // normalize role: 4 rows/block
        int row = blockIdx.x * 4 + wv;
        float2 v = ((const float2*)emb)[row * 64 + lane];
        float ss = fmaf(v.x, v.x, v.y * v.y);
#pragma unroll
        for (int m = 1; m < 64; m <<= 1) ss += __shfl_xor(ss, m, 64);
        float inv = 1.0f / fmaxf(sqrtf(ss), 1e-12f);
        bf16x2 o; o.x = (bf16_t)(v.x * inv); o.y = (bf16_t)(v.y * inv);
        *(bf16x2*)(xsw + swz(row, lane)) = o;
        if (threadIdx.x < 4) se_acc[blockIdx.x * 4 + threadIdx.x] = 0.f;
        if (blockIdx.x == 0 && threadIdx.x == 0) *done = 0;
        return;
    }

    int cls = blockIdx.x - 2048;         // csum role: classes 0..999
    if (threadIdx.x < DIM) cs[threadIdx.x] = 0.f;
    if (threadIdx.x == 0) nrows = 0;
    __syncthreads();
    float s0 = 0.f, s1 = 0.f;
    const int4* lab4 = (const int4*)(labels + wv * 2048);   // wave's quarter
#pragma unroll
    for (int it = 0; it < 8; ++it) {
        int4 l = lab4[it * 64 + lane];
        int base = wv * 2048 + it * 256;
#pragma unroll
        for (int cmp = 0; cmp < 4; ++cmp) {
            int li = (cmp == 0) ? l.x : (cmp == 1) ? l.y : (cmp == 2) ? l.z : l.w;
            unsigned long long m = __ballot(li == cls);
            while (m) {                  // wave-uniform; ~2 rows/wave avg
                int bb = __builtin_ctzll(m);
                m &= m - 1;
                int row = base + 4 * bb + cmp;
                float2 v = ((const float2*)emb)[row * 64 + lane];
                float ss = fmaf(v.x, v.x, v.y * v.y);
#pragma unroll
                for (int mm = 1; mm < 64; mm <<= 1) ss += __shfl_xor(ss, mm, 64);
                float inv = 1.0f / fmaxf(sqrtf(ss), 1e-12f);
                bf16x2 o; o.x = (bf16_t)(v.x * inv); o.y = (bf16_t)(v.y * inv);
                float x0 = (float)o.x, x1 = (float)o.y;
                float sdp = fmaf(x0, x0, x1 * x1);          // bf16-rounded selfdot
#pragma unroll
                for (int mm = 1; mm < 64; mm <<= 1) sdp += __shfl_xor(sdp, mm, 64);
                s0 += x0; s1 += x1;
                if (lane == 0) sd_arr[row] = sdp;
                int idx = 0;
                if (lane == 0) idx = atomicAdd(&nrows, 1);
                idx = __shfl(idx, 0, 64);
                if (idx < 96) {
                    xloc[idx][lane] = o;
                    if (lane == 0) rowlist[idx] = row;
                }
            }
        }
    }
    atomicAdd(&cs[2 * lane], s0);
    atomicAdd(&cs[2 * lane + 1], s1);
    __syncthreads();
    int n = nrows;
    float cm1v = (float)(n - 1);
    for (int k = wv; k < n; k += 4) {    // per-row cd from completed class sum
        bf16x2 xv = xloc[k][lane];
        float x0 = (float)xv.x, x1 = (float)xv.y;
        float cdp = fmaf(x0, cs[2 * lane], x1 * cs[2 * lane + 1]);
#pragma unroll
        for (int mm = 1; mm < 64; mm <<= 1) cdp += __shfl_xor(cdp, mm, 64);
        if (lane == 0) {
            int row = rowlist[k];
            cd_arr[row] = cdp;
            cm1_arr[row] = cm1v;
        }
    }
}

// --- B: triangular Gram main + last-block finalize ---
// Block = (cq, g): 128-col chunk staged to LDS once; wave wv -> row band
// I = 4g+wv (I <= 4cq+3). C layout (m74/m101): col = lane&31,
// row = (r&3) + 8*(r>>2) + 4*(lane>>5).
__global__ __launch_bounds__(256, 4) void main_kernel(const bf16_t* __restrict__ xsw,
                                                      const float* __restrict__ cd_arr,
                                                      const float* __restrict__ sd_arr,
                                                      const float* __restrict__ cm1_arr,
                                                      float* __restrict__ se_acc,
                                                      int* __restrict__ done,
                                                      float* __restrict__ out) {
    __shared__ bf16_t bst[4 * 4096];     // 32 KB shared B chunk
    __shared__ float cols[128];
    __shared__ int amlast;
    if (threadIdx.x < 128) cols[threadIdx.x] = 0.f;

    int b = blockIdx.x;                  // triangular decode
    int cq = (int)((sqrtf(8.f * (float)b + 1.f) - 1.f) * 0.5f);
    while ((cq + 1) * (cq + 2) / 2 <= b) ++cq;
    while (cq * (cq + 1) / 2 > b) --cq;
    int g = b - cq * (cq + 1) / 2;

    int wv = threadIdx.x >> 6, lane = threadIdx.x & 63;
    int I = 4 * g + wv;
    int c = lane & 31, h = lane >> 5;
    int laneoff = h * 256 + c * 8;

    const bf16_t* abase = xsw + (size_t)I * 4096 + laneoff;
    bf16x8 a[8];
#pragma unroll
    for (int f = 0; f < 8; ++f) a[f] = *(const bf16x8*)(abase + f * 512);

    {   // stage the block's shared 32 KB B-chunk
        const uint4* gsrc = (const uint4*)(xsw + (size_t)cq * 4 * 4096);
        uint4* ldst = (uint4*)bst;
#pragma unroll
        for (int i = 0; i < 8; ++i)
            ldst[i * 256 + threadIdx.x] = gsrc[i * 256 + threadIdx.x];
    }
    __syncthreads();

    float se[16];
#pragma unroll
    for (int r = 0; r < 16; ++r) se[r] = 0.f;
    float colacc[4] = {0.f, 0.f, 0.f, 0.f};

#pragma unroll
    for (int t = 0; t < 4; ++t) {
        const bf16_t* bt = bst + t * 4096 + laneoff;
        bf16x8 bfr[8];
#pragma unroll
        for (int f = 0; f < 8; ++f) bfr[f] = *(const bf16x8*)(bt + f * 512);
        f32x16 acc;
#pragma unroll
        for (int r = 0; r < 16; ++r) acc[r] = 0.f;
#pragma unroll
        for (int f = 0; f < 8; ++f)
            acc = __builtin_amdgcn_mfma_f32_32x32x16_bf16(a[f], bfr[f], acc, 0, 0, 0);
        int ct = cq * 4 + t;
        if (ct >= I) {                   // wave-uniform mask
            float c0 = 0.f, c1 = 0.f, c2 = 0.f, c3 = 0.f;
#pragma unroll
            for (int r = 0; r < 16; ++r) {
                float e = __builtin_amdgcn_exp2f(fmaf(acc[r], L2E10, -L2E10));
                se[r] += e;
                if ((r & 3) == 0) c0 += e; else if ((r & 3) == 1) c1 += e;
                else if ((r & 3) == 2) c2 += e; else c3 += e;
            }
            if (ct > I) colacc[t] = (c0 + c1) + (c2 + c3);
        }
    }

    // row-side: reduce over 32 col-lanes, atomic into se_acc
#pragma unroll
    for (int r = 0; r < 16; ++r) {
        float vv = se[r];
#pragma unroll
        for (int m = 1; m < 32; m <<= 1) vv += __shfl_xor(vv, m, 64);
        se[r] = vv;
    }
    if (c == 0) {
        int rowbase = I * 32 + 4 * h;
#pragma unroll
        for (int r = 0; r < 16; ++r)
            atomicAdd(&se_acc[rowbase + (r & 3) + 8 * (r >> 2)], se[r]);
    }

    // col-side: combine halves, LDS-combine 4 waves (same cq), flush once
#pragma unroll
    for (int t = 0; t < 4; ++t) {
        float v = colacc[t] + __shfl_xor(colacc[t], 32, 64);
        if (h == 0) atomicAdd(&cols[t * 32 + c], v);
    }
    __syncthreads();
    if (threadIdx.x < 128)
        atomicAdd(&se_acc[cq * 128 + threadIdx.x], cols[threadIdx.x]);

    // --- completion protocol: last block finalizes ---
    __threadfence();                     // make this block's atomics visible
    __syncthreads();                     // all threads' atomics issued+fenced
    if (threadIdx.x == 0) amlast = (atomicAdd(done, 1) == NJOBS - 1);
    __syncthreads();
    if (!amlast) return;
    __threadfence();                     // acquire: see all blocks' se_acc

    float lsum = 0.f;
    for (int i = threadIdx.x; i < NN; i += 256) {
        float sdv = sd_arr[i], cdv = cd_arr[i], cm1 = cm1_arr[i];
        float diag = __builtin_amdgcn_exp2f(fmaf(sdv, L2E10, -L2E10));
        float sev  = fmaxf(se_acc[i] - diag, 1e-30f);
        float lse  = fmaf(__builtin_amdgcn_logf(sev), LN2, 10.f);
        lsum += (cm1 * lse - 10.f * (cdv - sdv)) / (cm1 + SMALL_VAL);
    }
#pragma unroll
    for (int m = 1; m < 64; m <<= 1) lsum += __shfl_xor(lsum, m, 64);
    if (lane == 0) cols[wv] = lsum;      // reuse cols for block partials
    __syncthreads();
    if (threadIdx.x == 0) *out = cols[0] + cols[1] + cols[2] + cols[3];
}

extern "C" void kernel_launch(void* const* d_in, const int* in_sizes, int n_in,
                              void* d_out, int out_size, void* d_ws, size_t ws_size,
                              hipStream_t stream) {
    const float* emb  = (const float*)d_in[0];
    const int* labels = (const int*)d_in[1];

    char* ws = (char*)d_ws;
    bf16_t* xsw = (bf16_t*)ws;                          // 2 MB swizzled normalized X
    float* se   = (float*)(ws + (size_t)NN * DIM * 2);  // 32 KB
    float* cd   = se + NN;
    float* sd   = cd + NN;
    float* cm1  = sd + NN;
    int*   done = (int*)(cm1 + NN);

    prep_kernel<<<2048 + 1000, 256, 0, stream>>>(emb, labels, xsw, cd, sd, cm1, se, done);
    main_kernel<<<NJOBS, 256, 0, stream>>>(xsw, cd, sd, cm1, se, done, (float*)d_out);
}

// Round 9
// 103.209 us; speedup vs baseline: 2.1171x; 2.1171x over previous
//
#include <hip/hip_runtime.h>
#include <hip/hip_bf16.h>

// SupCon loss, N=8192, D=128, T=0.1.
// R8: 3 regular nodes (R5 pipeline restored; R7's per-block __threadfence
// caused 2080 L2-writebacks = +110us — removed).
//   1) norm_csum  (verbatim R5): per-class ballot-scan; normalize member rows,
//      LDS class-sum, per-row cd/sd/cm1; zeroes se_acc/out.
//   2) main_kernel (NEW): flat WAVE-level triangular jobs, ZERO LDS, no
//      __syncthreads. Wave = (band I, segment s of its J>=I sweep, SEGS=32).
//      B-frags direct from L1/L2 (1KB coalesced loads); se[16] accumulated
//      across the whole segment -> one 80-bpermute row-reduce per ~8 tiles;
//      col-side = 1 shuffle + one 32-lane atomic per tile.
//   3) finalize   (verbatim R5): elementwise loss + sum.
//
// Math: loss_i = (cm1_i*lse_i - 10*(cd_i - sd_i))/(cm1_i+tiny)
//   lse_i = 10 + ln(sum_{j!=i} e^{s_ij-10})  (constant shift exact; s<=10)
//   cd_i = x_i . classsum[lab_i], sd_i = x_i . x_i (bf16-rounded, matches MFMA)
//   se accumulated INCLUDING diagonal? No: diagonal tile masks c==row (e=0);
//   finalize subtracts nothing here — wait: diag masked in-kernel, but sd-based
//   diag subtraction retained for exactness of the OTHER path: see note below.
//   NOTE: diagonal handled IN-KERNEL (e=0 on the J==I tile), so finalize's
//   diag subtraction is REMOVED (was only needed when diag was included).
//   Symmetry: tile (I,J): J>I feeds rows AND cols; J==I rows only (full tile
//   lies within band I, transpose elements included).

typedef __bf16 bf16_t;
typedef __bf16 bf16x2 __attribute__((ext_vector_type(2)));
typedef __bf16 bf16x8 __attribute__((ext_vector_type(8)));
typedef float f32x16 __attribute__((ext_vector_type(16)));

#define NN 8192
#define DIM 128
#define NB 256                    // 32-row bands
#define SEGS 32                   // segments per band -> 8192 wave-jobs
#define SMALL_VAL 1.17549435e-38f
#define L2E10 14.4269504089f      // 10*log2(e)
#define LN2 0.69314718056f

// Swizzle: X[row][d] at (row>>5)*4096 + (d>>4)*512 + ((d>>3)&1)*256 + (row&31)*8 + (d&7)
// Lane l holds dims (2l,2l+1): f=l>>3, hh=(l>>2)&1, j=(l&3)*2 (pair contiguous).
__device__ inline size_t swz(int row, int lane) {
    int f = lane >> 3, hh = (lane >> 2) & 1, j = (lane & 3) << 1;
    return ((size_t)(row >> 5) * 4096) + f * 512 + hh * 256 + (row & 31) * 8 + j;
}

// --- 1: fused normalize + class-sum + per-row finalize scalars (R5) ---
__global__ __launch_bounds__(256) void norm_csum(const float* __restrict__ emb,
                                                 const int* __restrict__ labels,
                                                 bf16_t* __restrict__ xsw,
                                                 float* __restrict__ cd_arr,
                                                 float* __restrict__ sd_arr,
                                                 float* __restrict__ cm1_arr,
                                                 float* __restrict__ se_acc,
                                                 float* __restrict__ out) {
    __shared__ float cs[DIM];
    __shared__ int rowlist[96];
    __shared__ int nrows;
    int cls = blockIdx.x;                      // 1024 blocks; labels < 1000
    int wv = threadIdx.x >> 6, lane = threadIdx.x & 63;
    if (threadIdx.x < DIM) cs[threadIdx.x] = 0.f;
    if (threadIdx.x == 0) nrows = 0;
    if (threadIdx.x < 8) se_acc[cls * 8 + threadIdx.x] = 0.f;   // zero all 8192
    if (cls == 0 && threadIdx.x == 0) *out = 0.f;
    __syncthreads();

    float s0 = 0.f, s1 = 0.f;
    const int4* lab4 = (const int4*)(labels + wv * 2048);       // wave's quarter
#pragma unroll
    for (int it = 0; it < 8; ++it) {
        int4 l = lab4[it * 64 + lane];
        int base = wv * 2048 + it * 256;
#pragma unroll
        for (int cmp = 0; cmp < 4; ++cmp) {
            int li = (cmp == 0) ? l.x : (cmp == 1) ? l.y : (cmp == 2) ? l.z : l.w;
            unsigned long long m = __ballot(li == cls);
            while (m) {                         // wave-uniform; ~2 rows/wave avg
                int bb = __builtin_ctzll(m);
                m &= m - 1;
                int row = base + 4 * bb + cmp;
                float2 v = ((const float2*)emb)[row * 64 + lane];
                float ss = fmaf(v.x, v.x, v.y * v.y);
#pragma unroll
                for (int mm = 1; mm < 64; mm <<= 1) ss += __shfl_xor(ss, mm, 64);
                float inv = 1.0f / fmaxf(sqrtf(ss), 1e-12f);
                bf16x2 o; o.x = (bf16_t)(v.x * inv); o.y = (bf16_t)(v.y * inv);
                *(bf16x2*)(xsw + swz(row, lane)) = o;
                s0 += (float)o.x; s1 += (float)o.y;     // bf16-rounded, matches MFMA
                if (lane == 0) {
                    int idx = atomicAdd(&nrows, 1);
                    if (idx < 96) rowlist[idx] = row;
                }
            }
        }
    }
    atomicAdd(&cs[2 * lane], s0);
    atomicAdd(&cs[2 * lane + 1], s1);
    __syncthreads();
    int n = nrows;
    for (int k = wv; k < n; k += 4) {          // per-row cd/sd
        int row = rowlist[k];
        bf16x2 xv = *(const bf16x2*)(xsw + swz(row, lane));
        float x0 = (float)xv.x, x1 = (float)xv.y;
        float cdp = fmaf(x0, cs[2 * lane], x1 * cs[2 * lane + 1]);
        float sdp = fmaf(x0, x0, x1 * x1);
#pragma unroll
        for (int mm = 1; mm < 64; mm <<= 1) {
            cdp += __shfl_xor(cdp, mm, 64);
            sdp += __shfl_xor(sdp, mm, 64);
        }
        if (lane == 0) {
            cd_arr[row] = cdp; sd_arr[row] = sdp; cm1_arr[row] = (float)(n - 1);
        }
    }
}

// --- 2: flat wave-job triangular Gram. Wave wid -> band I = wid>>5, seg
// s = wid&31 covering tiles J in [I + NT*s/32, I + NT*(s+1)/32), NT = 256-I.
// C layout (m74/m101): col = lane&31, row = (r&3) + 8*(r>>2) + 4*(lane>>5).
__global__ __launch_bounds__(256, 4) void main_kernel(const bf16_t* __restrict__ xsw,
                                                      float* __restrict__ se_acc) {
    int wid  = blockIdx.x * 4 + (threadIdx.x >> 6);
    int lane = threadIdx.x & 63;
    int I = wid >> 5, s = wid & 31;
    int NT = NB - I;
    int t0 = (NT * s) >> 5, t1 = (NT * (s + 1)) >> 5;
    if (t0 == t1) return;                      // empty segment

    int c = lane & 31, h = lane >> 5;
    int laneoff = h * 256 + c * 8;

    const bf16_t* abase = xsw + (size_t)I * 4096 + laneoff;
    bf16x8 a[8];
#pragma unroll
    for (int f = 0; f < 8; ++f) a[f] = *(const bf16x8*)(abase + f * 512);

    float se[16];
#pragma unroll
    for (int r = 0; r < 16; ++r) se[r] = 0.f;

    for (int t = t0; t < t1; ++t) {
        int J = I + t;
        const bf16_t* bbase = xsw + (size_t)J * 4096 + laneoff;
        bf16x8 b[8];
#pragma unroll
        for (int f = 0; f < 8; ++f) b[f] = *(const bf16x8*)(bbase + f * 512);
        f32x16 acc;
#pragma unroll
        for (int r = 0; r < 16; ++r) acc[r] = 0.f;
#pragma unroll
        for (int f = 0; f < 8; ++f)
            acc = __builtin_amdgcn_mfma_f32_32x32x16_bf16(a[f], b[f], acc, 0, 0, 0);

        if (J == I) {                          // diagonal tile: mask c==row, rows only
#pragma unroll
            for (int r = 0; r < 16; ++r) {
                bool isdiag = c == ((r & 3) + 8 * (r >> 2) + 4 * h);
                float e = isdiag ? 0.f
                                 : __builtin_amdgcn_exp2f(fmaf(acc[r], L2E10, -L2E10));
                se[r] += e;
            }
        } else {                               // off-diag: rows + transpose cols
            float c0 = 0.f, c1 = 0.f, c2 = 0.f, c3 = 0.f;
#pragma unroll
            for (int r = 0; r < 16; ++r) {
                float e = __builtin_amdgcn_exp2f(fmaf(acc[r], L2E10, -L2E10));
                se[r] += e;
                if ((r & 3) == 0) c0 += e; else if ((r & 3) == 1) c1 += e;
                else if ((r & 3) == 2) c2 += e; else c3 += e;
            }
            float v = (c0 + c1) + (c2 + c3);   // this lane's 16-row col partial
            v += __shfl_xor(v, 32, 64);        // + other half's 16 rows
            if (h == 0) atomicAdd(&se_acc[J * 32 + c], v);
        }
    }

    // row-side: reduce se[r] over the 32 c-lanes of each half, flush once
#pragma unroll
    for (int r = 0; r < 16; ++r) {
        float vv = se[r];
#pragma unroll
        for (int m = 1; m < 32; m <<= 1) vv += __shfl_xor(vv, m, 64);
        se[r] = vv;
    }
    if (c == 0) {
        int rowbase = I * 32 + 4 * h;
#pragma unroll
        for (int r = 0; r < 16; ++r)
            atomicAdd(&se_acc[rowbase + (r & 3) + 8 * (r >> 2)], se[r]);
    }
}

// --- 3: elementwise finalize (diag already excluded in main) ---
__global__ __launch_bounds__(256) void finalize_kernel(const float* __restrict__ se_acc,
                                                       const float* __restrict__ cd_arr,
                                                       const float* __restrict__ sd_arr,
                                                       const float* __restrict__ cm1_arr,
                                                       float* __restrict__ out) {
    __shared__ float part[4];
    int i = blockIdx.x * 256 + threadIdx.x;
    float sd = sd_arr[i], cd = cd_arr[i], cm1 = cm1_arr[i];
    float sev  = fmaxf(se_acc[i], 1e-30f);
    float lse  = fmaf(__builtin_amdgcn_logf(sev), LN2, 10.f);
    float loss = (cm1 * lse - 10.f * (cd - sd)) / (cm1 + SMALL_VAL);
#pragma unroll
    for (int m = 1; m < 64; m <<= 1) loss += __shfl_xor(loss, m, 64);
    int wv = threadIdx.x >> 6;
    if ((threadIdx.x & 63) == 0) part[wv] = loss;
    __syncthreads();
    if (threadIdx.x == 0) atomicAdd(out, part[0] + part[1] + part[2] + part[3]);
}

extern "C" void kernel_launch(void* const* d_in, const int* in_sizes, int n_in,
                              void* d_out, int out_size, void* d_ws, size_t ws_size,
                              hipStream_t stream) {
    const float* emb  = (const float*)d_in[0];
    const int* labels = (const int*)d_in[1];

    char* ws = (char*)d_ws;
    bf16_t* xsw = (bf16_t*)ws;                          // 2 MB swizzled normalized X
    float* se   = (float*)(ws + (size_t)NN * DIM * 2);  // 32 KB
    float* cd   = se + NN;
    float* sd   = cd + NN;
    float* cm1  = sd + NN;

    norm_csum<<<1024, 256, 0, stream>>>(emb, labels, xsw, cd, sd, cm1, se, (float*)d_out);
    main_kernel<<<NB * SEGS / 4, 256, 0, stream>>>(xsw, se);
    finalize_kernel<<<NN / 256, 256, 0, stream>>>(se, cd, sd, cm1, (float*)d_out);
}